// Round 1
// 1512.787 us; speedup vs baseline: 1.8737x; 1.8737x over previous
//
#include <hip/hip_runtime.h>
#include <math.h>

#define NB 32
#define KIN 32768
#define HID 2048
#define NOUT 65536
#define SPLITK1 128
#define KCH1 (KIN / SPLITK1)    // 256
#define SPLITK2 4
#define KCH2 (HID / SPLITK2)    // 512

// ws layout (float offsets). P region is time-shared:
//   phase A (k1/k2): P1[SPLITK1][NB][HID]   = 128*32*2048  = 8,388,608 floats
//   phase B (k3/k3r): P2[SPLITK2][NB][NOUT] = 4*32*65536   = 8,388,608 floats
static constexpr size_t Y_OFF  = 0;                                    // 2,097,152
static constexpr size_t P_OFF  = (size_t)NB * NOUT;                    // 8,388,608
static constexpr size_t H_OFF  = P_OFF + (size_t)8388608;              // 65,536
static constexpr size_t GP_OFF = H_OFF + (size_t)NB * HID;             // 1,048,576
static constexpr size_t A_OFF  = GP_OFF + (size_t)32 * 32 * 1024;      // 32,768
// total ~11.63M floats = 46.5 MB

// ---------------- GEMM1 split-K partials: P[ky][m][n] = sum_k x[m,k]*W1[k,n] ----------------
__global__ __launch_bounds__(256) void k1_gemm1(const float* __restrict__ x,
                                                const float* __restrict__ W1,
                                                float* __restrict__ P) {
  const int n  = blockIdx.x * 256 + threadIdx.x;   // 0..2047
  const int kb = blockIdx.y * KCH1;
  float acc[NB];
#pragma unroll
  for (int m = 0; m < NB; ++m) acc[m] = 0.f;
#pragma unroll 1
  for (int k0 = 0; k0 < KCH1; k0 += 16) {
    float w[16];
#pragma unroll
    for (int u = 0; u < 16; ++u)
      w[u] = __builtin_nontemporal_load(&W1[(size_t)(kb + k0 + u) * HID + n]);
#pragma unroll
    for (int m = 0; m < NB; ++m) {
      const float* xp = &x[(size_t)m * KIN + kb + k0];  // wave-uniform -> s_load
#pragma unroll
      for (int u = 0; u < 16; ++u) acc[m] = fmaf(xp[u], w[u], acc[m]);
    }
  }
  float* p = P + (size_t)blockIdx.y * (NB * HID);
#pragma unroll
  for (int m = 0; m < NB; ++m) p[(size_t)m * HID + n] = acc[m];
}

// ---------------- reduce split-K + bias + exact GELU -> H[m][n] ----------------
__global__ __launch_bounds__(256) void k2_reduce_gelu(const float* __restrict__ P,
                                                      const float* __restrict__ b1,
                                                      float* __restrict__ H) {
  const int t = blockIdx.x * 256 + threadIdx.x;    // 0..65535
  float s0 = 0.f, s1 = 0.f, s2 = 0.f, s3 = 0.f;
#pragma unroll 8
  for (int ky = 0; ky < SPLITK1; ky += 4) {
    s0 += P[(size_t)(ky + 0) * (NB * HID) + t];
    s1 += P[(size_t)(ky + 1) * (NB * HID) + t];
    s2 += P[(size_t)(ky + 2) * (NB * HID) + t];
    s3 += P[(size_t)(ky + 3) * (NB * HID) + t];
  }
  float s = (s0 + s1) + (s2 + s3);
  s += b1[t & (HID - 1)];
  H[t] = 0.5f * s * (1.f + erff(s * 0.70710678118654752440f));
}

// ---------------- GEMM2 split-K partials: P[ky][m][n2] = sum_{k in chunk} H[m,k]*W2[k,n2] ----------------
__global__ __launch_bounds__(256) void k3_gemm2(const float* __restrict__ H,
                                                const float* __restrict__ W2,
                                                float* __restrict__ P) {
  const int n  = blockIdx.x * 256 + threadIdx.x;   // 0..65535
  const int kb = blockIdx.y * KCH2;
  float acc[NB];
#pragma unroll
  for (int m = 0; m < NB; ++m) acc[m] = 0.f;
#pragma unroll 1
  for (int k0 = 0; k0 < KCH2; k0 += 16) {
    float w[16];
#pragma unroll
    for (int u = 0; u < 16; ++u)
      w[u] = __builtin_nontemporal_load(&W2[(size_t)(kb + k0 + u) * NOUT + n]);
#pragma unroll
    for (int m = 0; m < NB; ++m) {
      const float* hp = &H[(size_t)m * HID + kb + k0];   // wave-uniform -> s_load
#pragma unroll
      for (int u = 0; u < 16; ++u) acc[m] = fmaf(hp[u], w[u], acc[m]);
    }
  }
  float* p = P + (size_t)blockIdx.y * ((size_t)NB * NOUT);
#pragma unroll
  for (int m = 0; m < NB; ++m) p[(size_t)m * NOUT + n] = acc[m];
}

// ---------------- reduce GEMM2 split-K + bias -> Y ----------------
__global__ __launch_bounds__(256) void k3r_reduce_bias(const float* __restrict__ P,
                                                       const float* __restrict__ b2,
                                                       float* __restrict__ Y) {
  const size_t t = (size_t)blockIdx.x * 256 + threadIdx.x;  // 0..NB*NOUT-1
  float s = 0.f;
#pragma unroll
  for (int ky = 0; ky < SPLITK2; ++ky) s += P[(size_t)ky * ((size_t)NB * NOUT) + t];
  Y[t] = s + b2[t & (NOUT - 1)];
}

// ---------------- per-batch Gram partials over 64-row chunks ----------------
__global__ __launch_bounds__(64) void k4_gram(const float* __restrict__ Y,
                                              float* __restrict__ GP) {
  const int b = blockIdx.x, ch = blockIdx.y;
  const int lane = threadIdx.x;
  const int bi = lane >> 3, bj = lane & 7;         // 4x4 block of G per lane
  const float* yb = Y + (size_t)b * NOUT + (size_t)ch * 64 * 32;
  float a[4][4];
#pragma unroll
  for (int p = 0; p < 4; ++p)
#pragma unroll
    for (int q = 0; q < 4; ++q) a[p][q] = 0.f;
#pragma unroll 4
  for (int rr = 0; rr < 64; ++rr) {
    const float* row = yb + rr * 32;
    float4 v4a = *(const float4*)(row + 4 * bi);
    float4 v4b = *(const float4*)(row + 4 * bj);
    float va[4] = {v4a.x, v4a.y, v4a.z, v4a.w};
    float vb[4] = {v4b.x, v4b.y, v4b.z, v4b.w};
#pragma unroll
    for (int p = 0; p < 4; ++p)
#pragma unroll
      for (int q = 0; q < 4; ++q) a[p][q] = fmaf(va[p], vb[q], a[p][q]);
  }
  float* gp = GP + ((size_t)b * 32 + ch) * 1024;
#pragma unroll
  for (int p = 0; p < 4; ++p)
#pragma unroll
    for (int q = 0; q < 4; ++q) gp[(4 * bi + p) * 32 + (4 * bj + q)] = a[p][q];
}

// ---------------- per-batch: Gram reduce, Cholesky, R^-1, LAPACK sign-LU, A = R^-1 * D ----------------
__global__ __launch_bounds__(64) void k5_small(const float* __restrict__ GP,
                                               const float* __restrict__ Y,
                                               float* __restrict__ A) {
  __shared__ float Gw[1024], Rm[1024], Ri[1024], Qt[1024], V[1024];
  __shared__ float uBs[32], wbuf[32], dsg[32];
  const int b = blockIdx.x;
  const int lane = threadIdx.x;

  // reduce Gram partials
  for (int e = lane; e < 1024; e += 64) {
    float s = 0.f;
    for (int ch = 0; ch < 32; ++ch) s += GP[((size_t)b * 32 + ch) * 1024 + e];
    Gw[e] = s;
  }
  __syncthreads();

  // Cholesky: G = R^T R (upper R in Rm)
  for (int k = 0; k < 32; ++k) {
    if (lane >= k && lane < 32) {
      float d = sqrtf(Gw[k * 32 + k]);
      Rm[k * 32 + lane] = Gw[k * 32 + lane] / d;   // lane==k gives d itself
    }
    __syncthreads();
    for (int e = lane; e < 1024; e += 64) {
      int i = e >> 5, j = e & 31;
      if (i > k && j > k) Gw[e] -= Rm[k * 32 + i] * Rm[k * 32 + j];
    }
    __syncthreads();
  }

  // Ri = R^-1 (upper). Lane c solves R x = e_c by back-substitution.
  if (lane < 32) {
    const int c = lane;
    for (int i = 31; i >= 0; --i) {
      float s = (i == c) ? 1.f : 0.f;
      for (int j = i + 1; j < 32; ++j) s -= Rm[i * 32 + j] * Ri[j * 32 + c];
      Ri[i * 32 + c] = s / Rm[i * 32 + i];
    }
  }
  __syncthreads();

  // Qt = Ytop(32x32) @ Ri  (reuse Gw as Ytop staging)
  for (int e = lane; e < 1024; e += 64) Gw[e] = Y[(size_t)b * NOUT + e];
  __syncthreads();
  for (int e = lane; e < 1024; e += 64) {
    int r = e >> 5, c = e & 31;
    float s = 0.f;
    for (int i = 0; i < 32; ++i) s += Gw[r * 32 + i] * Ri[i * 32 + c];
    Qt[e] = s;
  }
  __syncthreads();

  // Sign-LU (Householder reconstruction on the top block): M = I - Qt*D = V*U,
  // choose d_i so that tau_i = u_ii = 1 - d_i*c_i >= 1 (LAPACK convention).
  for (int i = 0; i < 32; ++i) {
    if (lane < i) uBs[lane] = Qt[lane * 32 + i];
    __syncthreads();
    for (int j = 0; j + 1 < i; ++j) {            // forward solve uB = L_prefix^-1 q_i
      if (lane > j && lane < i) uBs[lane] -= V[lane * 32 + j] * uBs[j];
      __syncthreads();
    }
    if (lane >= i && lane < 32) {                // residual w_r = q_i[r] - V[r,:i] uB
      float wv = Qt[lane * 32 + i];
      for (int j = 0; j < i; ++j) wv -= V[lane * 32 + j] * uBs[j];
      wbuf[lane] = wv;
    }
    __syncthreads();
    const float c = wbuf[i];
    const float d = (c > 0.f) ? -1.f : 1.f;      // d_i = -sign(c)
    const float uii = 1.f - d * c;               // = 1 + |c| in [1,2]
    if (lane == i) dsg[i] = d;
    if (lane > i && lane < 32) V[lane * 32 + i] = -d * wbuf[lane] / uii;
    __syncthreads();
  }

  // A = Ri * diag(d)
  for (int e = lane; e < 1024; e += 64) A[(size_t)b * 1024 + e] = Ri[e] * dsg[e & 31];
}

// ---------------- Q = Y_b @ A_b, one row per thread ----------------
__global__ __launch_bounds__(256) void k6_apply(const float* __restrict__ Y,
                                               const float* __restrict__ A,
                                               float* __restrict__ out) {
  const int b = blockIdx.x;
  const int r = blockIdx.y * 256 + threadIdx.x;
  const float* y  = Y + (size_t)b * NOUT + (size_t)r * 32;
  const float* Ab = A + (size_t)b * 1024;          // wave-uniform rows -> s_load
  float yr[32];
#pragma unroll
  for (int q = 0; q < 8; ++q) {
    float4 v = ((const float4*)y)[q];
    yr[4 * q] = v.x; yr[4 * q + 1] = v.y; yr[4 * q + 2] = v.z; yr[4 * q + 3] = v.w;
  }
  float acc[32];
#pragma unroll
  for (int c = 0; c < 32; ++c) acc[c] = 0.f;
#pragma unroll
  for (int i = 0; i < 32; ++i) {
#pragma unroll
    for (int c = 0; c < 32; ++c) acc[c] = fmaf(yr[i], Ab[i * 32 + c], acc[c]);
  }
  float* o = out + (size_t)b * NOUT + (size_t)r * 32;
#pragma unroll
  for (int q = 0; q < 8; ++q) {
    float4 v = {acc[4 * q], acc[4 * q + 1], acc[4 * q + 2], acc[4 * q + 3]};
    ((float4*)o)[q] = v;
  }
}

extern "C" void kernel_launch(void* const* d_in, const int* in_sizes, int n_in,
                              void* d_out, int out_size, void* d_ws, size_t ws_size,
                              hipStream_t stream) {
  const float* x  = (const float*)d_in[0];
  const float* W1 = (const float*)d_in[1];
  const float* b1 = (const float*)d_in[2];
  const float* W2 = (const float*)d_in[3];
  const float* b2 = (const float*)d_in[4];
  float* ws = (float*)d_ws;
  float* Y  = ws + Y_OFF;
  float* P  = ws + P_OFF;   // time-shared: P1 (k1/k2) then P2 (k3/k3r)
  float* H  = ws + H_OFF;
  float* GP = ws + GP_OFF;
  float* Aa = ws + A_OFF;
  float* out = (float*)d_out;

  k1_gemm1<<<dim3(HID / 256, SPLITK1), 256, 0, stream>>>(x, W1, P);
  k2_reduce_gelu<<<dim3((NB * HID) / 256), 256, 0, stream>>>(P, b1, H);
  k3_gemm2<<<dim3(NOUT / 256, SPLITK2), 256, 0, stream>>>(H, W2, P);
  k3r_reduce_bias<<<dim3((NB * NOUT) / 256), 256, 0, stream>>>(P, b2, Y);
  k4_gram<<<dim3(NB, 32), 64, 0, stream>>>(Y, GP);
  k5_small<<<dim3(NB), 64, 0, stream>>>(GP, Y, Aa);
  k6_apply<<<dim3(NB, 2048 / 256), 256, 0, stream>>>(Y, Aa, out);
}